// Round 11
// baseline (155.685 us; speedup 1.0000x reference)
//
#include <hip/hip_runtime.h>
#include <hip/hip_bf16.h>

// Problem constants (B,S,D,H fixed by setup_inputs)
#define B_  8
#define S_  1024
#define D_  768
#define H_  12
#define DH_ 64

typedef __attribute__((ext_vector_type(8))) short bf16x8;
typedef __attribute__((ext_vector_type(4))) float f32x4;
typedef __attribute__((ext_vector_type(16))) float f32x16;

__device__ inline short f2bf(float f) {
    unsigned u = __builtin_bit_cast(unsigned, f);
    u = (u + 0x7fffu + ((u >> 16) & 1u)) >> 16;   // RNE
    return (short)u;
}
__device__ inline float exp2_fast(float x) {
    float r; asm("v_exp_f32 %0, %1" : "=v"(r) : "v"(x)); return r;
}
__device__ inline unsigned cvt_pk_bf16(float lo, float hi) {
    unsigned r; asm("v_cvt_pk_bf16_f32 %0, %1, %2" : "=v"(r) : "v"(lo), "v"(hi)); return r;
}
__device__ inline float rcp_fast(float x) {
    float r; asm("v_rcp_f32 %0, %1" : "=v"(r) : "v"(x)); return r;
}
__device__ inline void plswap(unsigned& a, unsigned& b) {
    auto r = __builtin_amdgcn_permlane32_swap(a, b, false, false);
    a = r[0]; b = r[1];
}
__device__ inline float2 xhalves(float x) {
    unsigned u = __builtin_bit_cast(unsigned, x);
    auto r = __builtin_amdgcn_permlane32_swap(u, u, false, false);
    return make_float2(__builtin_bit_cast(float, r[0]),
                       __builtin_bit_cast(float, r[1]));
}
// Async global->LDS, 16B/lane. LDS dest = wave-uniform base + lane*16;
// swizzle lives in the per-lane GLOBAL source address (rule 21).
__device__ inline void gl_lds16(const void* gsrc, char* ldst) {
    __builtin_amdgcn_global_load_lds(
        (const __attribute__((address_space(1))) unsigned int*)gsrc,
        (__attribute__((address_space(3))) unsigned int*)ldst,
        16, 0, 0);
}

// ---------------------------------------------------------------------------
// Kernel 0: W f32 -> bf16 (one-time). 589824 elems, 8 per thread.
// ---------------------------------------------------------------------------
__global__ __launch_bounds__(256) void convw_kernel(
    const float* __restrict__ W, short* __restrict__ Wb)
{
    int i = (blockIdx.x * 256 + threadIdx.x) * 8;
    f32x4 a = *(const f32x4*)(W + i);
    f32x4 b = *(const f32x4*)(W + i + 4);
    uint4 pk;
    pk.x = cvt_pk_bf16(a[0], a[1]); pk.y = cvt_pk_bf16(a[2], a[3]);
    pk.z = cvt_pk_bf16(b[0], b[1]); pk.w = cvt_pk_bf16(b[2], b[3]);
    *(uint4*)(Wb + i) = pk;
}

// ---------------------------------------------------------------------------
// Kernel 1 (v7): Y = relu(X @ W^T) — m97-replica with bf16 LDS operands.
// 128x128 tile, BK=64 (12 steps), 4 waves 2x2, 32 MFMA/wave/step.
// B = Wb bf16 via gl_lds16 (source pre-swizzled c^(r&7), linear LDS dest).
// A = X f32 reg-prefetched 1 step ahead -> cvt_pk -> swizzled ds_write_b128
//     (bf16 in LDS: half the read bytes of v6, 2x dup instead of 8x).
// LDS traffic/block-step: 32KB write + 64KB read per 64 K-units (4.3x < v6).
// Counted vmcnt(8): gl_lds drained, A-prefetch stays in flight.
// 32KB LDS single buffer + epilogue overlay; ~3 blocks/CU.
// ---------------------------------------------------------------------------
__global__ __launch_bounds__(256) void proj_kernel(
    const float* __restrict__ q, const float* __restrict__ k,
    const float* __restrict__ v, const short* __restrict__ Wb,
    short* __restrict__ q1, short* __restrict__ k1, short* __restrict__ v1t)
{
    __shared__ __align__(16) char lds[32768];   // A 16K | B 16K; epilogue overlay

    int p  = blockIdx.x;
    int L  = (p & 7) * 144 + (p >> 3);   // 1152 = 8 XCD x 144
    int mt = L / 6, nt = L % 6;
    int t  = mt >> 6;                    // 0=q,1=k,2=v
    int m0 = (mt & 63) << 7;
    int n0 = nt << 7;
    const float* X = (t == 0) ? q : (t == 1) ? k : v;

    int tid = threadIdx.x, lane = tid & 63, w = tid >> 6;
    int wr = w >> 1, wc = w & 1;
    int l15 = lane & 15, g = lane >> 4;

    // --- B staging (gl_lds): wave w covers B rows [w*32, w*32+32) ---
    const short* bsrc[4];
    char*        bdst[4];
    #pragma unroll
    for (int i = 0; i < 4; i++) {
        int r = w * 32 + i * 8 + (lane >> 3);
        int c = lane & 7;
        bsrc[i] = Wb + (size_t)(n0 + r) * D_ + ((c ^ (r & 7)) << 3);
        bdst[i] = lds + 16384 + w * 4096 + i * 1024;
    }

    // --- A staging (reg + cvt + ds_write): thread -> row tr, 32-col half ch ---
    int tr = tid >> 1, ch = tid & 1;
    const float* asrc = X + (size_t)(m0 + tr) * D_ + ch * 32;
    int awb[4];
    #pragma unroll
    for (int j = 0; j < 4; j++)
        awb[j] = tr * 128 + (((4 * ch + j) ^ (tr & 7)) << 4);

    f32x4 pf[8];
#define LOADA(s_) do { \
        _Pragma("unroll") \
        for (int j = 0; j < 8; j++) \
            pf[j] = *(const f32x4*)(asrc + (s_) * 64 + j * 4); \
    } while (0)

    f32x4 acc[4][4];
    #pragma unroll
    for (int m = 0; m < 4; m++)
        #pragma unroll
        for (int n = 0; n < 4; n++) acc[m][n] = (f32x4){0.f, 0.f, 0.f, 0.f};

    LOADA(0);
    for (int s = 0; s < 12; ++s) {
        __builtin_amdgcn_s_barrier();            // prev step's LDS reads done
        asm volatile("" ::: "memory");
        #pragma unroll
        for (int i = 0; i < 4; i++)
            gl_lds16(bsrc[i] + s * 64, bdst[i]);
        // cvt + A writes (from prefetched regs)
        #pragma unroll
        for (int j = 0; j < 4; j++) {
            uint4 u;
            u.x = cvt_pk_bf16(pf[2 * j][0], pf[2 * j][1]);
            u.y = cvt_pk_bf16(pf[2 * j][2], pf[2 * j][3]);
            u.z = cvt_pk_bf16(pf[2 * j + 1][0], pf[2 * j + 1][1]);
            u.w = cvt_pk_bf16(pf[2 * j + 1][2], pf[2 * j + 1][3]);
            *(uint4*)(lds + awb[j]) = u;
        }
        if (s + 1 < 12) {
            LOADA(s + 1);                        // 8 prefetch loads in flight
            asm volatile("s_waitcnt vmcnt(8) lgkmcnt(0)" ::: "memory");
        } else {
            asm volatile("s_waitcnt vmcnt(0) lgkmcnt(0)" ::: "memory");
        }
        __builtin_amdgcn_s_barrier();            // tile ready for all waves
        asm volatile("" ::: "memory");

        #pragma unroll
        for (int kk = 0; kk < 2; kk++) {
            bf16x8 af[4], bfv[4];
            #pragma unroll
            for (int m = 0; m < 4; m++) {
                int ra = wr * 64 + m * 16 + l15;
                af[m] = *(const bf16x8*)(lds + ra * 128 +
                         ((((kk << 2) | g) ^ (ra & 7)) << 4));
            }
            #pragma unroll
            for (int n = 0; n < 4; n++) {
                int rb = wc * 64 + n * 16 + l15;
                bfv[n] = *(const bf16x8*)(lds + 16384 + rb * 128 +
                          ((((kk << 2) | g) ^ (rb & 7)) << 4));
            }
            __builtin_amdgcn_s_setprio(1);
            #pragma unroll
            for (int m = 0; m < 4; m++)
                #pragma unroll
                for (int n = 0; n < 4; n++)
                    acc[m][n] = __builtin_amdgcn_mfma_f32_16x16x32_bf16(
                        af[m], bfv[n], acc[m][n], 0, 0, 0);
            __builtin_amdgcn_s_setprio(0);
        }
    }
#undef LOADA

    // Epilogue: relu(+scale) -> bf16 -> swizzled-LDS transpose -> b128 stores.
    // Ts: 128 rows x 16 slots of 16B; byte = r*256 + ((slot^(r&15))<<4) + (c&7)*2
    __syncthreads();
    const float sc1 = (t == 1) ? 0.18033688011112793f : 1.0f;  // 1/8*log2(e)
    #pragma unroll
    for (int m = 0; m < 4; m++) {
        int rb = wr * 64 + m * 16 + (g << 2);
        #pragma unroll
        for (int n = 0; n < 4; n++) {
            int cb = wc * 64 + n * 16 + l15;
            #pragma unroll
            for (int r = 0; r < 4; r++) {
                short vv = f2bf(fmaxf(acc[m][n][r], 0.f) * sc1);
                int rr = (t == 2) ? cb : rb + r;     // v: store transposed
                int cc = (t == 2) ? rb + r : cb;
                *(short*)(lds + rr * 256 + (((cc >> 3) ^ (rr & 15)) << 4)
                          + ((cc & 7) << 1)) = vv;
            }
        }
    }
    __syncthreads();
    int row = tid >> 1;
    int c0  = (tid & 1) << 6;
    bf16x8 ov[8];
    #pragma unroll
    for (int j = 0; j < 8; j++)
        ov[j] = *(const bf16x8*)(lds + row * 256 +
                 ((((c0 >> 3) + j) ^ (row & 15)) << 4));
    if (t == 2) {
        int gc = n0 + row;
        int hh2 = gc >> 6, dh = gc & 63;
        int bb = m0 >> 10, s0 = m0 & 1023;
        short* dst = v1t + (((size_t)bb * H_ + hh2) * DH_ + dh) * S_ + s0 + c0;
        #pragma unroll
        for (int j = 0; j < 8; j++) *(bf16x8*)(dst + j * 8) = ov[j];
    } else {
        int m = m0 + row;
        int bb = m >> 10, ss = m & 1023;
        int hh2 = (n0 >> 6) + (tid & 1);
        short* dst = (t ? k1 : q1) + (((size_t)bb * H_ + hh2) * S_ + ss) * DH_;
        #pragma unroll
        for (int j = 0; j < 8; j++) *(bf16x8*)(dst + j * 8) = ov[j];
    }
}

// ---------------------------------------------------------------------------
// Kernel 2 (v5): flash attention, swapped-QK^T 32x32x16, block-cooperative
// LDS-staged K/V (unchanged from round 6 -- passing, fast).
// ---------------------------------------------------------------------------
__global__ __launch_bounds__(256, 3) void attn_kernel(
    const short* __restrict__ q1, const short* __restrict__ k1,
    const short* __restrict__ v1t, float* __restrict__ out)
{
    __shared__ short Klds[2][4096];
    __shared__ short Vlds[2][4096];
    __shared__ float lsum_lds[4][32];

    int d    = blockIdx.x;
    int head = (d & 7) + ((d >> 6) << 3);
    int qi   = (d >> 3) & 7;
    int bb   = head / H_, hh = head % H_;

    int tid = threadIdx.x, lane = tid & 63, w = tid >> 6;
    int l31 = lane & 31, hi = lane >> 5;
    int qbase = (qi * 4 + w) * 32;

    const short* Qp = q1  + (size_t)head * S_ * DH_;
    const short* Kp = k1  + (size_t)head * S_ * DH_;
    const short* Vp = v1t + (size_t)head * DH_ * S_;

    int sr = tid >> 2, sc = tid & 3;
    int swz0 = sr * 128 + ((sc       ^ (sr & 7)) << 4);
    int swz1 = sr * 128 + (((sc + 4) ^ (sr & 7)) << 4);

    bf16x8 stK0, stK1, stV0, stV1;

#define LOADST(kvb) do { \
        const short* _kg = Kp + (size_t)((kvb) + sr) * DH_; \
        const short* _vg = Vp + (size_t)sr * S_ + (kvb); \
        stK0 = *(const bf16x8*)(_kg + sc * 8); \
        stK1 = *(const bf16x8*)(_kg + (sc + 4) * 8); \
        stV0 = *(const bf16x8*)(_vg + sc * 8); \
        stV1 = *(const bf16x8*)(_vg + (sc + 4) * 8); \
    } while (0)
#define WRITEST(buf) do { \
        char* _kb = (char*)&Klds[buf][0]; \
        char* _vb = (char*)&Vlds[buf][0]; \
        *(bf16x8*)(_kb + swz0) = stK0; \
        *(bf16x8*)(_kb + swz1) = stK1; \
        *(bf16x8*)(_vb + swz0) = stV0; \
        *(bf16x8*)(_vb + swz1) = stV1; \
    } while (0)

    bf16x8 qf[4];
    #pragma unroll
    for (int kb = 0; kb < 4; kb++)
        qf[kb] = *(const bf16x8*)(Qp + (size_t)(qbase + l31) * DH_ + kb * 16 + hi * 8);

    f32x16 o0, o1;
    #pragma unroll
    for (int r = 0; r < 16; r++) { o0[r] = 0.f; o1[r] = 0.f; }
    float mreg = -1e30f, lsum = 0.f;

    int xk = l31 & 7;

    auto subtile = [&](int cur, int j) {
        const char* Kt = (const char*)&Klds[cur][0];
        const char* Vt = (const char*)&Vlds[cur][0];
        int rK = (32 * j + l31) * 128;
        bf16x8 kf0 = *(const bf16x8*)(Kt + rK + (((0 + hi) ^ xk) << 4));
        bf16x8 kf1 = *(const bf16x8*)(Kt + rK + (((2 + hi) ^ xk) << 4));
        bf16x8 kf2 = *(const bf16x8*)(Kt + rK + (((4 + hi) ^ xk) << 4));
        bf16x8 kf3 = *(const bf16x8*)(Kt + rK + (((6 + hi) ^ xk) << 4));
        int rV0 = l31 * 128, rV1 = (32 + l31) * 128;
        int s0 = ((4 * j + hi) ^ xk) << 4, s1 = ((4 * j + 2 + hi) ^ xk) << 4;
        bf16x8 vf00 = *(const bf16x8*)(Vt + rV0 + s0);
        bf16x8 vf01 = *(const bf16x8*)(Vt + rV0 + s1);
        bf16x8 vf10 = *(const bf16x8*)(Vt + rV1 + s0);
        bf16x8 vf11 = *(const bf16x8*)(Vt + rV1 + s1);

        f32x16 s;
        #pragma unroll
        for (int r = 0; r < 16; r++) s[r] = 0.f;
        __builtin_amdgcn_s_setprio(1);
        s = __builtin_amdgcn_mfma_f32_32x32x16_bf16(kf0, qf[0], s, 0, 0, 0);
        s = __builtin_amdgcn_mfma_f32_32x32x16_bf16(kf1, qf[1], s, 0, 0, 0);
        s = __builtin_amdgcn_mfma_f32_32x32x16_bf16(kf2, qf[2], s, 0, 0, 0);
        s = __builtin_amdgcn_mfma_f32_32x32x16_bf16(kf3, qf[3], s, 0, 0, 0);
        __builtin_amdgcn_s_setprio(0);

        float t0 = fmaxf(s[0], s[1]),   t1 = fmaxf(s[2], s[3]);
        float t2 = fmaxf(s[4], s[5]),   t3 = fmaxf(s[6], s[7]);
        float t4 = fmaxf(s[8], s[9]),   t5 = fmaxf(s[10], s[11]);
        float t6 = fmaxf(s[12], s[13]), t7 = fmaxf(s[14], s[15]);
        float u0 = fmaxf(t0, t1), u1 = fmaxf(t2, t3);
        float u2 = fmaxf(t4, t5), u3 = fmaxf(t6, t7);
        float pmax = fmaxf(fmaxf(u0, u1), fmaxf(u2, u3));
        float2 ph = xhalves(pmax);
        pmax = fmaxf(ph.x, ph.y);

        if (!__all(pmax <= mreg + 8.f)) {
            float mn = fmaxf(mreg, pmax);
            float sc_ = exp2_fast(mreg - mn);
            mreg = mn; lsum *= sc_;
            if (hi == 0) lsum_lds[w][l31] = sc_;
            asm volatile("s_waitcnt lgkmcnt(0)" ::: "memory");
            #pragma unroll
            for (int r = 0; r < 16; r++) {
                int crow = (r & 3) + ((r >> 2) << 3) + (hi << 2);
                float srw = lsum_lds[w][crow];
                o0[r] *= srw; o1[r] *= srw;
            }
        }

        #pragma unroll
        for (int r = 0; r < 16; r++) s[r] = exp2_fast(s[r] - mreg);

        float a0 = s[0] + s[1],   a1 = s[2] + s[3];
        float a2 = s[4] + s[5],   a3 = s[6] + s[7];
        float a4 = s[8] + s[9],   a5 = s[10] + s[11];
        float a6 = s[12] + s[13], a7 = s[14] + s[15];
        float rsum = ((a0 + a1) + (a2 + a3)) + ((a4 + a5) + (a6 + a7));
        float2 rh = xhalves(rsum);
        lsum += rh.x + rh.y;

        unsigned c0 = cvt_pk_bf16(s[0], s[1]);
        unsigned c1 = cvt_pk_bf16(s[2], s[3]);
        unsigned c2 = cvt_pk_bf16(s[4], s[5]);
        unsigned c3 = cvt_pk_bf16(s[6], s[7]);
        unsigned c4 = cvt_pk_bf16(s[8], s[9]);
        unsigned c5 = cvt_pk_bf16(s[10], s[11]);
        unsigned c6 = cvt_pk_bf16(s[12], s[13]);
        unsigned c7 = cvt_pk_bf16(s[14], s[15]);
        plswap(c0, c2);
        plswap(c1, c3);
        plswap(c4, c6);
        plswap(c5, c7);

        union U { unsigned u[4]; bf16x8 v; };
        U f0, f1;
        f0.u[0] = c0; f0.u[1] = c1; f0.u[2] = c2; f0.u[3] = c3;
        f1.u[0] = c4; f1.u[1] = c5; f1.u[2] = c6; f1.u[3] = c7;

        __builtin_amdgcn_s_setprio(1);
        o0 = __builtin_amdgcn_mfma_f32_32x32x16_bf16(f0.v, vf00, o0, 0, 0, 0);
        o0 = __builtin_amdgcn_mfma_f32_32x32x16_bf16(f1.v, vf01, o0, 0, 0, 0);
        o1 = __builtin_amdgcn_mfma_f32_32x32x16_bf16(f0.v, vf10, o1, 0, 0, 0);
        o1 = __builtin_amdgcn_mfma_f32_32x32x16_bf16(f1.v, vf11, o1, 0, 0, 0);
        __builtin_amdgcn_s_setprio(0);
    };

    LOADST(0);
    WRITEST(0);
    LOADST(64);
    asm volatile("s_waitcnt lgkmcnt(0)" ::: "memory");
    __builtin_amdgcn_s_barrier();
    asm volatile("" ::: "memory");

    int cur = 0;
    for (int t = 0; t < 16; t++) {
        if (t < 15) {
            WRITEST(cur ^ 1);
            if (t < 14) LOADST((t + 2) * 64);
        }
        subtile(cur, 0);
        subtile(cur, 1);
        if (t < 15) {
            asm volatile("" ::: "memory");
            asm volatile("s_waitcnt lgkmcnt(0)" ::: "memory");
            __builtin_amdgcn_s_barrier();
            asm volatile("" ::: "memory");
        }
        cur ^= 1;
    }
#undef LOADST
#undef WRITEST

    if (hi == 0) lsum_lds[w][l31] = lsum;
    asm volatile("s_waitcnt lgkmcnt(0)" ::: "memory");
    #pragma unroll
    for (int r = 0; r < 16; r++) {
        int crow = (r & 3) + ((r >> 2) << 3) + (hi << 2);
        float inv = rcp_fast(lsum_lds[w][crow]);
        float* op = out + ((size_t)(bb * S_ + qbase + crow)) * D_ + hh * DH_ + l31;
        op[0]  = o0[r] * inv;
        op[32] = o1[r] * inv;
    }
}

// ---------------------------------------------------------------------------
// Kernel 3 (v2): y = LN(2*out + q) * gamma + beta; 192 thr/row, f32x4 loads.
// ---------------------------------------------------------------------------
__global__ __launch_bounds__(192) void ln_kernel(
    const float* __restrict__ qin, const float* __restrict__ gamma,
    const float* __restrict__ beta, float* __restrict__ out)
{
    int row = blockIdx.x;
    int tid = threadIdx.x;
    size_t base = (size_t)row * D_ + tid * 4;

    f32x4 o  = *(const f32x4*)(out + base);
    f32x4 qv = *(const f32x4*)(qin + base);
    f32x4 x;
    float sum = 0.f, sq = 0.f;
    #pragma unroll
    for (int i = 0; i < 4; i++) {
        x[i] = 2.f * o[i] + qv[i];
        sum += x[i];
        sq  += x[i] * x[i];
    }
    #pragma unroll
    for (int msk = 1; msk < 64; msk <<= 1) {
        sum += __shfl_xor(sum, msk);
        sq  += __shfl_xor(sq, msk);
    }
    __shared__ float s1[3], s2[3];
    if ((tid & 63) == 0) { s1[tid >> 6] = sum; s2[tid >> 6] = sq; }
    __syncthreads();
    sum = s1[0] + s1[1] + s1[2];
    sq  = s2[0] + s2[1] + s2[2];
    float mu   = sum * (1.f / D_);
    float var  = sq * (1.f / D_) - mu * mu;
    float rstd = rsqrtf(var + 1e-5f);
    f32x4 g = *(const f32x4*)(gamma + tid * 4);
    f32x4 b = *(const f32x4*)(beta + tid * 4);
    f32x4 y;
    #pragma unroll
    for (int i = 0; i < 4; i++)
        y[i] = (x[i] - mu) * rstd * g[i] + b[i];
    *(f32x4*)(out + base) = y;
}

// ---------------------------------------------------------------------------
extern "C" void kernel_launch(void* const* d_in, const int* in_sizes, int n_in,
                              void* d_out, int out_size, void* d_ws, size_t ws_size,
                              hipStream_t stream)
{
    const float* q     = (const float*)d_in[0];
    const float* k     = (const float*)d_in[1];
    const float* v     = (const float*)d_in[2];
    const float* W     = (const float*)d_in[3];
    const float* gamma = (const float*)d_in[4];
    const float* beta  = (const float*)d_in[5];

    size_t per = (size_t)B_ * H_ * S_ * DH_;   // 6291456
    short* q1  = (short*)d_ws;
    short* k1  = q1 + per;
    short* v1t = k1 + per;
    short* Wb  = v1t + per;                    // +1.18 MB
    float* out = (float*)d_out;

    convw_kernel<<<dim3(288), dim3(256), 0, stream>>>(W, Wb);
    // 192 m-tiles (3 inputs x 64) x 6 n-tiles = 1152 blocks
    proj_kernel<<<dim3(1152), dim3(256), 0, stream>>>(q, k, v, Wb, q1, k1, v1t);
    attn_kernel<<<dim3(768), dim3(256), 0, stream>>>(q1, k1, v1t, out);
    ln_kernel<<<dim3(B_ * S_), dim3(192), 0, stream>>>(q, gamma, beta, out);
}